// Round 4
// baseline (390.994 us; speedup 1.0000x reference)
//
#include <hip/hip_runtime.h>
#include <hip/hip_bf16.h>
#include <stdint.h>

// Problem constants (B, N, E, D) = (32, 4096, 8192, 128); all float io fp32.
// R2 post-mortem: atomic scatter 220us @1.5TB/s (atomic-bound), gemm ~310us
// (scattered 256B-stride B-fragment loads thrash L1). R3 (405.1us verified):
// CSR gather (no atomics, agg stored bf16) + LDS-staged weights (dbuf).
// R4 (no bench): gather scalarized via readfirstlane + unroll-2.
// R5 (no bench): weight-resident gemm (192KB bf16 weights -> 96 VGPR/wave,
// no LDS, no barriers, h_in epilogue re-read becomes L1 hit).
// R6 (no bench): afrag array eliminated (ko-outer convert) -> est VGPR ~190;
// counts-memset folded into transpose_weights.
// R7 (audit round, still no counters): CRITICAL FIX — gemm grid was
// MM/(128*TPB_GEMM)=128 blocks but each block covers 128 rows -> 7/8 of out
// unwritten. Corrected to MM/(16*TPB_GEMM)=1024. No other changes.
#define BB 32
#define NN 4096
#define EE 8192
#define DD 128
#define MM (BB * NN)        // 131072 rows
#define THREE_D (3 * DD)    // 384
#define CAP 32              // bucket capacity; deg~Poisson(2), P(deg>31)<1e-25

typedef __bf16 bf16x8 __attribute__((ext_vector_type(8)));
typedef __bf16 bf16x2 __attribute__((ext_vector_type(2)));
typedef float  f32x4  __attribute__((ext_vector_type(4)));
typedef float  f32x2  __attribute__((ext_vector_type(2)));

// ws layout
#define AGG_BYTES ((size_t)MM * DD * 2)           // 32 MiB, bf16 aggregate
#define WT_OFF    AGG_BYTES
#define WT_BYTES  ((size_t)2 * THREE_D * DD * 2)  // 192 KiB, bf16 [mat][col][k]
#define CNT_OFF   (WT_OFF + WT_BYTES)
#define CNT_BYTES ((size_t)MM * 4)                // 512 KiB
#define BKT_OFF   (CNT_OFF + CNT_BYTES)           // 16 MiB edge-id buckets

// ---------------------------------------------------------------------------
// Kernel 1: transpose + fp32->bf16 both weight matrices (D,3D)->(3D,D).
// Also zeroes the CSR counters (folds the old hipMemsetAsync dispatch).
// ---------------------------------------------------------------------------
__global__ void transpose_weights(const float* __restrict__ w0,
                                  const float* __restrict__ w1,
                                  __bf16* __restrict__ wt,
                                  int* __restrict__ counts) {
    int tid = blockIdx.x * blockDim.x + threadIdx.x;   // 0 .. 98303
    for (int i = tid; i < MM; i += 2 * THREE_D * DD)   // zero 131072 counters
        counts[i] = 0;
    int mat = tid / (THREE_D * DD);
    int rem = tid % (THREE_D * DD);
    int col = rem / DD;
    int k   = rem % DD;
    const float* src = mat ? w1 : w0;
    wt[tid] = (__bf16)src[k * THREE_D + col];
}

// ---------------------------------------------------------------------------
// Kernel 2: build CSR buckets. One thread per edge; atomicAdd on 131072
// counters only (cheap), store global edge id.
// ---------------------------------------------------------------------------
__global__ void scatter_ids(const int* __restrict__ conn,
                            int* __restrict__ counts,
                            int* __restrict__ bucket) {
    int e = blockIdx.x * 256 + threadIdx.x;            // 0 .. B*E-1
    int b = e >> 13;                                   // e / EE
    int2 pr = ((const int2*)conn)[e];                  // one 8B load, use .y
    int node = b * NN + pr.y;
    int pos = atomicAdd(&counts[node], 1);
    if (pos < CAP) bucket[node * CAP + pos] = e;
}

// ---------------------------------------------------------------------------
// Kernel 3: gather-aggregate. One wave per node; sum message rows (avg deg 2)
// with coalesced float2 loads; write agg as bf16 (feeds MFMA A directly).
// node wave-uniform via readfirstlane -> counts/bucket on the scalar pipe;
// unroll-by-2 so the two (avg) message-row loads have independent latency.
// ---------------------------------------------------------------------------
__global__ void gather_messages(const float* __restrict__ messages,
                                const int* __restrict__ counts,
                                const int* __restrict__ bucket,
                                __bf16* __restrict__ agg) {
    int node = __builtin_amdgcn_readfirstlane(blockIdx.x * 16 + (threadIdx.x >> 6));
    int lane = threadIdx.x & 63;
    int cnt = counts[node];                            // scalar load (SMEM)
    if (cnt > CAP) cnt = CAP;
    const int* bp = bucket + (size_t)node * CAP;
    float a0 = 0.f, a1 = 0.f;
    int i = 0;
    for (; i + 2 <= cnt; i += 2) {
        int e0 = bp[i];                                // scalar loads
        int e1 = bp[i + 1];
        f32x2 v0 = *(const f32x2*)(messages + (size_t)e0 * DD + lane * 2);
        f32x2 v1 = *(const f32x2*)(messages + (size_t)e1 * DD + lane * 2);
        a0 += v0[0] + v1[0];
        a1 += v0[1] + v1[1];
    }
    if (i < cnt) {
        int e = bp[i];
        f32x2 v = *(const f32x2*)(messages + (size_t)e * DD + lane * 2);
        a0 += v[0];
        a1 += v[1];
    }
    bf16x2 o;
    o[0] = (__bf16)a0;
    o[1] = (__bf16)a1;
    *(bf16x2*)(agg + (size_t)node * DD + lane * 2) = o;
}

// ---------------------------------------------------------------------------
// Kernel 4: fused dual-GEMM + GRU gates, weights REGISTER-resident.
// Block: 512 thr = 8 waves; wave w owns gate-col group g=w (16 cols) for all
// 3 parts x 2 matrices: 24 bf16x8 B-frags = 96 VGPR, loaded once from wt
// (L2-resident). Loop over 8 M-tiles of 16 rows: load A-tile, 24 MFMA,
// fused GRU epilogue. No LDS, no __syncthreads. Next-tile A-loads issued
// between MFMA and epilogue. ko-outer h->bf16 conversion via one transient
// hg keeps peak VGPR ~190 (< 256 cap @ 2 waves/EU).
// MFMA layouts (gfx950, verified): A[m=lane&15][k=quad*8+j],
// B[k=quad*8+j][n=lane&15], C/D: col=lane&15, row=quad*4+reg.
// ---------------------------------------------------------------------------
#define TPB_GEMM 8   // 16-row tiles per block; 128 rows/block -> 1024 blocks
__launch_bounds__(512, 2)
__global__ void gru_gemm_wreg(const __bf16* __restrict__ agg,
                              const float* __restrict__ h_in,
                              const __bf16* __restrict__ wt,
                              const float* __restrict__ bias,
                              float* __restrict__ out) {
    const int wave = threadIdx.x >> 6;                 // = gate col group g
    const int lane = threadIdx.x & 63;
    const int quad = lane >> 4;
    const int l16  = lane & 15;

    // Resident B fragments [p][m][ko]:
    // wt[(m*384 + p*128 + g*16 + l16)*128 + ko*32 + quad*8]
    bf16x8 bfrag[3][2][4];
    for (int p = 0; p < 3; ++p)
        for (int m = 0; m < 2; ++m)
            for (int ko = 0; ko < 4; ++ko)
                bfrag[p][m][ko] = *(const bf16x8*)(wt
                    + ((size_t)(m * THREE_D + p * 128 + wave * 16 + l16)) * DD
                    + ko * 32 + quad * 8);

    const int j = wave * 16 + l16;                     // gate index 0..127
    const float b0z = bias[j];
    const float b0r = bias[DD + j];
    const float b0h = bias[2 * DD + j];
    const float b1z = bias[THREE_D + j];
    const float b1r = bias[THREE_D + DD + j];
    const float b1h = bias[THREE_D + 2 * DD + j];

    const int tile0 = blockIdx.x * TPB_GEMM;

    bf16x8 a_raw[4];                                   // agg row fragment
    f32x4  h_raw[8];                                   // h row fragment (fp32)
    auto load_tile = [&](int tb) {
        int r = tb * 16 + l16;
        const __bf16* arow = agg  + (size_t)r * DD;
        const float*  hrow = h_in + (size_t)r * DD;
        for (int ko = 0; ko < 4; ++ko) {
            int k = ko * 32 + quad * 8;
            a_raw[ko]         = *(const bf16x8*)(arow + k);
            h_raw[ko * 2]     = *(const f32x4*)(hrow + k);
            h_raw[ko * 2 + 1] = *(const f32x4*)(hrow + k + 4);
        }
    };

    load_tile(tile0);
    for (int t = 0; t < TPB_GEMM; ++t) {
        const int tb = tile0 + t;

        f32x4 acc[3][2];                               // [part z/r/h][mat]
        for (int p = 0; p < 3; ++p)
            for (int m = 0; m < 2; ++m)
                acc[p][m] = (f32x4){0.f, 0.f, 0.f, 0.f};

        for (int ko = 0; ko < 4; ++ko) {
            bf16x8 hg;                                 // h -> bf16, this ko only
            for (int i = 0; i < 4; ++i) {
                hg[i]     = (__bf16)h_raw[ko * 2][i];
                hg[i + 4] = (__bf16)h_raw[ko * 2 + 1][i];
            }
            for (int p = 0; p < 3; ++p) {
                acc[p][0] = __builtin_amdgcn_mfma_f32_16x16x32_bf16(
                    a_raw[ko], bfrag[p][0][ko], acc[p][0], 0, 0, 0);
                acc[p][1] = __builtin_amdgcn_mfma_f32_16x16x32_bf16(
                    hg,        bfrag[p][1][ko], acc[p][1], 0, 0, 0);
            }
        }

        if (t + 1 < TPB_GEMM) load_tile(tb + 1);       // prefetch next A-tile

        for (int rr = 0; rr < 4; ++rr) {
            int row = tb * 16 + quad * 4 + rr;
            float xz  = acc[0][0][rr] + b0z;
            float rz  = acc[0][1][rr] + b1z;
            float xr  = acc[1][0][rr] + b0r;
            float rrg = acc[1][1][rr] + b1r;
            float xh  = acc[2][0][rr] + b0h;
            float rh  = acc[2][1][rr] + b1h;
            float z   = 1.f / (1.f + __expf(-(xz + rz)));
            float rg  = 1.f / (1.f + __expf(-(xr + rrg)));
            float pre = xh + rg * rh;
            float hh  = 2.f / (1.f + __expf(-2.f * pre)) - 1.f;  // tanh
            float hold = h_in[(size_t)row * DD + j];   // L1-hit (tile just read)
            float o = z * hold + (1.f - z) * hh;
            out[(size_t)row * DD + j] = o;
        }
    }
}

// ---------------------------------------------------------------------------
extern "C" void kernel_launch(void* const* d_in, const int* in_sizes, int n_in,
                              void* d_out, int out_size, void* d_ws, size_t ws_size,
                              hipStream_t stream) {
    const float* atom_state = (const float*)d_in[0];
    const float* messages   = (const float*)d_in[1];
    const int*   conn       = (const int*)d_in[2];
    const float* w0         = (const float*)d_in[3];
    const float* w1         = (const float*)d_in[4];
    const float* bias       = (const float*)d_in[5];
    float* out = (float*)d_out;

    __bf16* agg    = (__bf16*)d_ws;
    __bf16* wt     = (__bf16*)((char*)d_ws + WT_OFF);
    int*    counts = (int*)((char*)d_ws + CNT_OFF);
    int*    bucket = (int*)((char*)d_ws + BKT_OFF);

    transpose_weights<<<(2 * THREE_D * DD) / 256, 256, 0, stream>>>(w0, w1, wt, counts);
    scatter_ids<<<(BB * EE) / 256, 256, 0, stream>>>(conn, counts, bucket);
    gather_messages<<<MM / 16, 1024, 0, stream>>>(messages, counts, bucket, agg);
    gru_gemm_wreg<<<MM / (16 * TPB_GEMM), 512, 0, stream>>>(agg, atom_state, wt, bias, out);
}

// Round 6
// 362.412 us; speedup vs baseline: 1.0789x; 1.0789x over previous
//
#include <hip/hip_runtime.h>
#include <hip/hip_bf16.h>
#include <stdint.h>

// Problem constants (B, N, E, D) = (32, 4096, 8192, 128); all float io fp32.
// R3 (405.1us verified): CSR gather + LDS-staged-weights gemm.
// R4-R6 (no bench): gather scalarized; weight-resident gemm (no LDS/barriers).
// R7 (390.99us verified, absmax 0.0156): grid fix. Counters: gemm 138us,
// VGPR 116, MfmaUtil 7.5%, VALUBusy 25%, hbm 883GB/s, occ 21% -> pure
// latency-bound (prefetch distance = epilogue only ~150cyc vs ~900cyc HBM).
// VGPR=116 < ~190 natural demand proves the allocator REMATERIALIZES the wt
// B-frag loads in-loop rather than hold 96 regs resident.
// R8 (no bench): T14 async-STAGE gemm — A-tiles (12KB contiguous) double-
// buffered in LDS; per tile: barrier -> issue t+1 global loads (16B/thr) ->
// compute t from LDS -> ds_write t+1 into other buf. One barrier/tile.
// R9 (audit round, still no counters): launch_bounds (512,4)->(512,2).
// The hard 128 cap risked SCRATCH SPILL of acc/bfrag (allocator demand
// ~130-140); (512,2) is the R7-verified contract (116 VGPR, 0 spill) and
// <=128 regs still yields 4 waves/EU in HW. No other changes.
#define BB 32
#define NN 4096
#define EE 8192
#define DD 128
#define MM (BB * NN)        // 131072 rows
#define THREE_D (3 * DD)    // 384
#define CAP 32              // bucket capacity; deg~Poisson(2), P(deg>31)<1e-25

typedef __bf16 bf16x8 __attribute__((ext_vector_type(8)));
typedef __bf16 bf16x2 __attribute__((ext_vector_type(2)));
typedef float  f32x4  __attribute__((ext_vector_type(4)));
typedef float  f32x2  __attribute__((ext_vector_type(2)));

// ws layout
#define AGG_BYTES ((size_t)MM * DD * 2)           // 32 MiB, bf16 aggregate
#define WT_OFF    AGG_BYTES
#define WT_BYTES  ((size_t)2 * THREE_D * DD * 2)  // 192 KiB, bf16 [mat][col][k]
#define CNT_OFF   (WT_OFF + WT_BYTES)
#define CNT_BYTES ((size_t)MM * 4)                // 512 KiB
#define BKT_OFF   (CNT_OFF + CNT_BYTES)           // 16 MiB edge-id buckets

// ---------------------------------------------------------------------------
// Kernel 1: transpose + fp32->bf16 both weight matrices (D,3D)->(3D,D).
// Also zeroes the CSR counters.
// ---------------------------------------------------------------------------
__global__ void transpose_weights(const float* __restrict__ w0,
                                  const float* __restrict__ w1,
                                  __bf16* __restrict__ wt,
                                  int* __restrict__ counts) {
    int tid = blockIdx.x * blockDim.x + threadIdx.x;   // 0 .. 98303
    for (int i = tid; i < MM; i += 2 * THREE_D * DD)   // zero 131072 counters
        counts[i] = 0;
    int mat = tid / (THREE_D * DD);
    int rem = tid % (THREE_D * DD);
    int col = rem / DD;
    int k   = rem % DD;
    const float* src = mat ? w1 : w0;
    wt[tid] = (__bf16)src[k * THREE_D + col];
}

// ---------------------------------------------------------------------------
// Kernel 2: build CSR buckets. One thread per edge; atomicAdd on 131072
// counters only (cheap), store global edge id.
// ---------------------------------------------------------------------------
__global__ void scatter_ids(const int* __restrict__ conn,
                            int* __restrict__ counts,
                            int* __restrict__ bucket) {
    int e = blockIdx.x * 256 + threadIdx.x;            // 0 .. B*E-1
    int b = e >> 13;                                   // e / EE
    int2 pr = ((const int2*)conn)[e];                  // one 8B load, use .y
    int node = b * NN + pr.y;
    int pos = atomicAdd(&counts[node], 1);
    if (pos < CAP) bucket[node * CAP + pos] = e;
}

// ---------------------------------------------------------------------------
// Kernel 3: gather-aggregate. One wave per node; sum message rows (avg deg 2)
// with coalesced float2 loads; write agg as bf16 (feeds MFMA A directly).
// node wave-uniform via readfirstlane -> counts/bucket on the scalar pipe;
// unroll-by-2 so the two (avg) message-row loads have independent latency.
// ---------------------------------------------------------------------------
__global__ void gather_messages(const float* __restrict__ messages,
                                const int* __restrict__ counts,
                                const int* __restrict__ bucket,
                                __bf16* __restrict__ agg) {
    int node = __builtin_amdgcn_readfirstlane(blockIdx.x * 16 + (threadIdx.x >> 6));
    int lane = threadIdx.x & 63;
    int cnt = counts[node];                            // scalar load (SMEM)
    if (cnt > CAP) cnt = CAP;
    const int* bp = bucket + (size_t)node * CAP;
    float a0 = 0.f, a1 = 0.f;
    int i = 0;
    for (; i + 2 <= cnt; i += 2) {
        int e0 = bp[i];                                // scalar loads
        int e1 = bp[i + 1];
        f32x2 v0 = *(const f32x2*)(messages + (size_t)e0 * DD + lane * 2);
        f32x2 v1 = *(const f32x2*)(messages + (size_t)e1 * DD + lane * 2);
        a0 += v0[0] + v1[0];
        a1 += v0[1] + v1[1];
    }
    if (i < cnt) {
        int e = bp[i];
        f32x2 v = *(const f32x2*)(messages + (size_t)e * DD + lane * 2);
        a0 += v[0];
        a1 += v[1];
    }
    bf16x2 o;
    o[0] = (__bf16)a0;
    o[1] = (__bf16)a1;
    *(bf16x2*)(agg + (size_t)node * DD + lane * 2) = o;
}

// ---------------------------------------------------------------------------
// Kernel 4: fused dual-GEMM + GRU gates. Weights register-resident (or
// compiler-rematerialized from L2-hot wt); A-tiles pipelined through
// double-buffered LDS (T14 split: issue loads early, ds_write late).
// One barrier per 16-row tile; a full tile-compute of load cover.
// MFMA layouts (gfx950, verified): A[m=lane&15][k=quad*8+j],
// B[k=quad*8+j][n=lane&15], C/D: col=lane&15, row=quad*4+reg.
// ---------------------------------------------------------------------------
#define TPB_GEMM 8   // 16-row tiles per block; 128 rows/block -> 1024 blocks
#define AGP 136      // padded agg LDS row (bf16 elems; 272B, stride%128B=16B)
#define HP  132      // padded h   LDS row (f32 elems; 528B, stride%128B=16B)
__launch_bounds__(512, 2)
__global__ void gru_gemm_pipe(const __bf16* __restrict__ agg,
                              const float* __restrict__ h_in,
                              const __bf16* __restrict__ wt,
                              const float* __restrict__ bias,
                              float* __restrict__ out) {
    const int tid  = threadIdx.x;
    const int wave = tid >> 6;                         // = gate col group g
    const int lane = tid & 63;
    const int quad = lane >> 4;
    const int l16  = lane & 15;

    __shared__ __bf16 aT[2][16 * AGP];                 // 2 x 4.25 KiB
    __shared__ float  hT[2][16 * HP];                  // 2 x 8.25 KiB

    // Resident B fragments [p][m][ko]:
    // wt[(m*384 + p*128 + g*16 + l16)*128 + ko*32 + quad*8]
    bf16x8 bfrag[3][2][4];
    for (int p = 0; p < 3; ++p)
        for (int m = 0; m < 2; ++m)
            for (int ko = 0; ko < 4; ++ko)
                bfrag[p][m][ko] = *(const bf16x8*)(wt
                    + ((size_t)(m * THREE_D + p * 128 + wave * 16 + l16)) * DD
                    + ko * 32 + quad * 8);

    const int j = wave * 16 + l16;                     // gate index 0..127
    const float b0z = bias[j];
    const float b0r = bias[DD + j];
    const float b0h = bias[2 * DD + j];
    const float b1z = bias[THREE_D + j];
    const float b1r = bias[THREE_D + DD + j];
    const float b1h = bias[THREE_D + 2 * DD + j];

    const int tile0 = blockIdx.x * TPB_GEMM;

    // staging: tile = 16 rows x (256B agg + 512B h), both contiguous blocks.
    // threads 0..255: one 16B agg chunk; all 512: one 16B h chunk.
    bf16x8 sa;                                         // in-flight agg chunk
    f32x4  sh;                                         // in-flight h chunk
    auto load_regs = [&](int tb) {
        if (tid < 256)
            sa = *(const bf16x8*)(agg + (size_t)tb * 2048 + tid * 8);
        sh = *(const f32x4*)(h_in + (size_t)tb * 2048 + tid * 4);
    };
    auto write_lds = [&](int buf) {
        if (tid < 256)
            *(bf16x8*)&aT[buf][(tid >> 4) * AGP + (tid & 15) * 8] = sa;
        *(f32x4*)&hT[buf][(tid >> 5) * HP + (tid & 31) * 4] = sh;
    };

    load_regs(tile0);
    write_lds(0);
    int buf = 0;
    for (int t = 0; t < TPB_GEMM; ++t) {
        __syncthreads();                               // buf's tile staged
        const int tb = tile0 + t;
        if (t + 1 < TPB_GEMM) load_regs(tb + 1);       // issue early (T14)

        f32x4 acc[3][2];                               // [part z/r/h][mat]
        for (int p = 0; p < 3; ++p)
            for (int m = 0; m < 2; ++m)
                acc[p][m] = (f32x4){0.f, 0.f, 0.f, 0.f};

        for (int ko = 0; ko < 4; ++ko) {
            bf16x8 af = *(const bf16x8*)&aT[buf][l16 * AGP + ko * 32 + quad * 8];
            f32x4 h0 = *(const f32x4*)&hT[buf][l16 * HP + ko * 32 + quad * 8];
            f32x4 h1 = *(const f32x4*)&hT[buf][l16 * HP + ko * 32 + quad * 8 + 4];
            bf16x8 hg;
            for (int i = 0; i < 4; ++i) {
                hg[i]     = (__bf16)h0[i];
                hg[i + 4] = (__bf16)h1[i];
            }
            for (int p = 0; p < 3; ++p) {
                acc[p][0] = __builtin_amdgcn_mfma_f32_16x16x32_bf16(
                    af, bfrag[p][0][ko], acc[p][0], 0, 0, 0);
                acc[p][1] = __builtin_amdgcn_mfma_f32_16x16x32_bf16(
                    hg, bfrag[p][1][ko], acc[p][1], 0, 0, 0);
            }
        }

        for (int rr = 0; rr < 4; ++rr) {
            int rl  = quad * 4 + rr;                   // row within tile
            int row = tb * 16 + rl;
            float xz  = acc[0][0][rr] + b0z;
            float rz  = acc[0][1][rr] + b1z;
            float xr  = acc[1][0][rr] + b0r;
            float rrg = acc[1][1][rr] + b1r;
            float xh  = acc[2][0][rr] + b0h;
            float rh  = acc[2][1][rr] + b1h;
            float z   = 1.f / (1.f + __expf(-(xz + rz)));
            float rg  = 1.f / (1.f + __expf(-(xr + rrg)));
            float pre = xh + rg * rh;
            float hh  = 2.f / (1.f + __expf(-2.f * pre)) - 1.f;  // tanh
            float hold = hT[buf][rl * HP + j];         // fp32 h from LDS
            float o = z * hold + (1.f - z) * hh;
            out[(size_t)row * DD + j] = o;
        }

        if (t + 1 < TPB_GEMM) write_lds(buf ^ 1);      // land t+1 into other buf
        buf ^= 1;
    }
}

// ---------------------------------------------------------------------------
extern "C" void kernel_launch(void* const* d_in, const int* in_sizes, int n_in,
                              void* d_out, int out_size, void* d_ws, size_t ws_size,
                              hipStream_t stream) {
    const float* atom_state = (const float*)d_in[0];
    const float* messages   = (const float*)d_in[1];
    const int*   conn       = (const int*)d_in[2];
    const float* w0         = (const float*)d_in[3];
    const float* w1         = (const float*)d_in[4];
    const float* bias       = (const float*)d_in[5];
    float* out = (float*)d_out;

    __bf16* agg    = (__bf16*)d_ws;
    __bf16* wt     = (__bf16*)((char*)d_ws + WT_OFF);
    int*    counts = (int*)((char*)d_ws + CNT_OFF);
    int*    bucket = (int*)((char*)d_ws + BKT_OFF);

    transpose_weights<<<(2 * THREE_D * DD) / 256, 256, 0, stream>>>(w0, w1, wt, counts);
    scatter_ids<<<(BB * EE) / 256, 256, 0, stream>>>(conn, counts, bucket);
    gather_messages<<<MM / 16, 1024, 0, stream>>>(messages, counts, bucket, agg);
    gru_gemm_pipe<<<MM / (16 * TPB_GEMM), 512, 0, stream>>>(agg, atom_state, wt, bias, out);
}

// Round 7
// 345.948 us; speedup vs baseline: 1.1302x; 1.0476x over previous
//
#include <hip/hip_runtime.h>
#include <hip/hip_bf16.h>
#include <stdint.h>

// Problem constants (B, N, E, D) = (32, 4096, 8192, 128); all float io fp32.
// R3 (405.1us): CSR gather + LDS-staged-weights gemm. R7 (390.99us): wreg
// gemm 138us, latency-bound (MfmaUtil 7.5%, hbm 11%, occ 21%).
// R8/R9 (362.4us verified, absmax 0.0156): LDS-pipelined gemm 106us, VGPR 84,
// MfmaUtil 9.4%, VALUBusy 31%, hbm 1.13TB/s, occ ~21%, bank-conf 3.1M (~5us).
// All pipes idle -> per-tile barrier drain + 1 block/CU residency cap this
// structure. Remaining ~256us = gather (~100-130) + scatter + transpose +
// launch gaps; agg round-trip = 64MB.
// R10: FUSE gather into gemm staging. aT stage-loads replaced by in-kernel
// aggregation (threads 0-255: cnt + 8 speculative ids (int4 x2 from the
// contiguous bucket row) + <=4 predicated msg loads issued post-barrier;
// MFMA of tile t covers the latency; accumulate+cvt+ds_write post-MFMA).
// h-path and MFMA/epilogue byte-identical to verified R9. Kills gather
// kernel, 64MB agg round-trip, one launch. gemm memory pipes at 14% absorb
// the 134MB message traffic.
#define BB 32
#define NN 4096
#define EE 8192
#define DD 128
#define MM (BB * NN)        // 131072 rows
#define THREE_D (3 * DD)    // 384
#define CAP 32              // bucket capacity; deg~Poisson(2), P(deg>31)<1e-25
#define PF 8                // speculatively prefetched ids; P(cnt>8)=0.02%

typedef __bf16 bf16x8 __attribute__((ext_vector_type(8)));
typedef __bf16 bf16x2 __attribute__((ext_vector_type(2)));
typedef float  f32x4  __attribute__((ext_vector_type(4)));
typedef float  f32x2  __attribute__((ext_vector_type(2)));

// ws layout (agg region retained in layout; no longer written)
#define AGG_BYTES ((size_t)MM * DD * 2)           // 32 MiB (unused after R10)
#define WT_OFF    AGG_BYTES
#define WT_BYTES  ((size_t)2 * THREE_D * DD * 2)  // 192 KiB, bf16 [mat][col][k]
#define CNT_OFF   (WT_OFF + WT_BYTES)
#define CNT_BYTES ((size_t)MM * 4)                // 512 KiB
#define BKT_OFF   (CNT_OFF + CNT_BYTES)           // 16 MiB edge-id buckets

// ---------------------------------------------------------------------------
// Kernel 1: transpose + fp32->bf16 both weight matrices (D,3D)->(3D,D).
// Also zeroes the CSR counters.
// ---------------------------------------------------------------------------
__global__ void transpose_weights(const float* __restrict__ w0,
                                  const float* __restrict__ w1,
                                  __bf16* __restrict__ wt,
                                  int* __restrict__ counts) {
    int tid = blockIdx.x * blockDim.x + threadIdx.x;   // 0 .. 98303
    for (int i = tid; i < MM; i += 2 * THREE_D * DD)   // zero 131072 counters
        counts[i] = 0;
    int mat = tid / (THREE_D * DD);
    int rem = tid % (THREE_D * DD);
    int col = rem / DD;
    int k   = rem % DD;
    const float* src = mat ? w1 : w0;
    wt[tid] = (__bf16)src[k * THREE_D + col];
}

// ---------------------------------------------------------------------------
// Kernel 2: build CSR buckets. One thread per edge; atomicAdd on 131072
// counters only (cheap), store global edge id.
// ---------------------------------------------------------------------------
__global__ void scatter_ids(const int* __restrict__ conn,
                            int* __restrict__ counts,
                            int* __restrict__ bucket) {
    int e = blockIdx.x * 256 + threadIdx.x;            // 0 .. B*E-1
    int b = e >> 13;                                   // e / EE
    int2 pr = ((const int2*)conn)[e];                  // one 8B load, use .y
    int node = b * NN + pr.y;
    int pos = atomicAdd(&counts[node], 1);
    if (pos < CAP) bucket[node * CAP + pos] = e;
}

// ---------------------------------------------------------------------------
// Kernel 3: fused gather + dual-GEMM + GRU gates.
// 512 thr = 8 waves; wave w owns gate-col group g=w. Per 16-row tile,
// double-buffered LDS staging:
//   threads 0-255 (waves 0-3): aggregate tile t+1 -> aT[buf^1]
//     (r=tid>>4, 8-float chunk c=tid&15): post-barrier load cnt + ids[0..7]
//     (2x int4 from contiguous bucket row) + issue <=4 predicated msg loads;
//     after MFMA of t: accumulate, batch-2 for cnt>4, rare tail, cvt bf16,
//     ds_write.
//   all 512: h fp32 16B chunk -> hT[buf^1] (load early / ds_write late, T14).
// MFMA layouts (gfx950, verified): A[m=lane&15][k=quad*8+j],
// B[k=quad*8+j][n=lane&15], C/D: col=lane&15, row=quad*4+reg.
// ---------------------------------------------------------------------------
#define TPB_GEMM 8   // 16-row tiles per block; 128 rows/block -> 1024 blocks
#define AGP 136      // padded agg LDS row (bf16 elems; 272B)
#define HP  132      // padded h   LDS row (f32 elems; 528B)
__launch_bounds__(512, 2)
__global__ void gru_gemm_fused(const float* __restrict__ messages,
                               const int* __restrict__ counts,
                               const int* __restrict__ bucket,
                               const float* __restrict__ h_in,
                               const __bf16* __restrict__ wt,
                               const float* __restrict__ bias,
                               float* __restrict__ out) {
    const int tid  = threadIdx.x;
    const int wave = tid >> 6;                         // = gate col group g
    const int lane = tid & 63;
    const int quad = lane >> 4;
    const int l16  = lane & 15;

    __shared__ __bf16 aT[2][16 * AGP];                 // 2 x 4.25 KiB
    __shared__ float  hT[2][16 * HP];                  // 2 x 8.25 KiB

    // Resident/rematerialized B fragments [p][m][ko]:
    // wt[(m*384 + p*128 + g*16 + l16)*128 + ko*32 + quad*8]
    bf16x8 bfrag[3][2][4];
    for (int p = 0; p < 3; ++p)
        for (int m = 0; m < 2; ++m)
            for (int ko = 0; ko < 4; ++ko)
                bfrag[p][m][ko] = *(const bf16x8*)(wt
                    + ((size_t)(m * THREE_D + p * 128 + wave * 16 + l16)) * DD
                    + ko * 32 + quad * 8);

    const int j = wave * 16 + l16;                     // gate index 0..127
    const float b0z = bias[j];
    const float b0r = bias[DD + j];
    const float b0h = bias[2 * DD + j];
    const float b1z = bias[THREE_D + j];
    const float b1r = bias[THREE_D + DD + j];
    const float b1h = bias[THREE_D + 2 * DD + j];

    const int tile0 = blockIdx.x * TPB_GEMM;

    // ---- h staging (all 512 threads, 16B each) ----
    f32x4 sh;
    auto load_h = [&](int tb) {
        sh = *(const f32x4*)(h_in + (size_t)tb * 2048 + tid * 4);
    };
    auto write_h = [&](int bf) {
        *(f32x4*)&hT[bf][(tid >> 5) * HP + (tid & 31) * 4] = sh;
    };

    // ---- aggregate staging (threads 0-255) ----
    const int ar = tid >> 4;                           // row in tile, 0..15
    const int ac = (tid & 15) * 8;                     // first of 8 elems
    int cnt = 0;
    int ids[PF];
    f32x4 ma[4], mb[4];                                // batch-1 in flight
    auto agg_issue = [&](int tb) {
        if (tid < 256) {
            int node = tb * 16 + ar;
            cnt = counts[node];
            if (cnt > CAP) cnt = CAP;
            *(int4*)&ids[0] = *(const int4*)(bucket + (size_t)node * CAP);
            *(int4*)&ids[4] = *(const int4*)(bucket + (size_t)node * CAP + 4);
            // predicated-address loads: safe row 0 when beyond cnt
            for (int i = 0; i < 4; ++i) {
                int e = (i < cnt) ? ids[i] : 0;
                ma[i] = *(const f32x4*)(messages + (size_t)e * DD + ac);
                mb[i] = *(const f32x4*)(messages + (size_t)e * DD + ac + 4);
            }
        }
    };
    auto agg_finish = [&](int tb, int bf) {
        if (tid < 256) {
            f32x4 s0 = (f32x4){0.f, 0.f, 0.f, 0.f};
            f32x4 s1 = (f32x4){0.f, 0.f, 0.f, 0.f};
            for (int i = 0; i < 4; ++i)
                if (i < cnt) { s0 += ma[i]; s1 += mb[i]; }
            if (cnt > 4) {                             // ~5% of rows
                for (int i = 4; i < 8; ++i) {
                    int e = (i < cnt) ? ids[i] : 0;
                    f32x4 va = *(const f32x4*)(messages + (size_t)e * DD + ac);
                    f32x4 vb = *(const f32x4*)(messages + (size_t)e * DD + ac + 4);
                    if (i < cnt) { s0 += va; s1 += vb; }
                }
                for (int i = PF; i < cnt; ++i) {       // P(cnt>8)=0.02%
                    int e = bucket[(size_t)(tb * 16 + ar) * CAP + i];
                    s0 += *(const f32x4*)(messages + (size_t)e * DD + ac);
                    s1 += *(const f32x4*)(messages + (size_t)e * DD + ac + 4);
                }
            }
            bf16x8 o;
            for (int q = 0; q < 4; ++q) {
                o[q]     = (__bf16)s0[q];
                o[q + 4] = (__bf16)s1[q];
            }
            *(bf16x8*)&aT[bf][ar * AGP + ac] = o;
        }
    };

    // prologue: stage tile0 into buf 0 (cold, full latency once)
    agg_issue(tile0);
    load_h(tile0);
    agg_finish(tile0, 0);
    write_h(0);

    int buf = 0;
    for (int t = 0; t < TPB_GEMM; ++t) {
        __syncthreads();                               // buf's tile staged
        const int tb = tile0 + t;
        if (t + 1 < TPB_GEMM) {                        // issue early (T14)
            agg_issue(tb + 1);
            load_h(tb + 1);
        }

        f32x4 acc[3][2];                               // [part z/r/h][mat]
        for (int p = 0; p < 3; ++p)
            for (int m = 0; m < 2; ++m)
                acc[p][m] = (f32x4){0.f, 0.f, 0.f, 0.f};

        for (int ko = 0; ko < 4; ++ko) {
            bf16x8 af = *(const bf16x8*)&aT[buf][l16 * AGP + ko * 32 + quad * 8];
            f32x4 h0 = *(const f32x4*)&hT[buf][l16 * HP + ko * 32 + quad * 8];
            f32x4 h1 = *(const f32x4*)&hT[buf][l16 * HP + ko * 32 + quad * 8 + 4];
            bf16x8 hg;
            for (int i = 0; i < 4; ++i) {
                hg[i]     = (__bf16)h0[i];
                hg[i + 4] = (__bf16)h1[i];
            }
            for (int p = 0; p < 3; ++p) {
                acc[p][0] = __builtin_amdgcn_mfma_f32_16x16x32_bf16(
                    af, bfrag[p][0][ko], acc[p][0], 0, 0, 0);
                acc[p][1] = __builtin_amdgcn_mfma_f32_16x16x32_bf16(
                    hg, bfrag[p][1][ko], acc[p][1], 0, 0, 0);
            }
        }

        if (t + 1 < TPB_GEMM) agg_finish(tb + 1, buf ^ 1);  // msgs landed

        for (int rr = 0; rr < 4; ++rr) {
            int rl  = quad * 4 + rr;                   // row within tile
            int row = tb * 16 + rl;
            float xz  = acc[0][0][rr] + b0z;
            float rz  = acc[0][1][rr] + b1z;
            float xr  = acc[1][0][rr] + b0r;
            float rrg = acc[1][1][rr] + b1r;
            float xh  = acc[2][0][rr] + b0h;
            float rh  = acc[2][1][rr] + b1h;
            float z   = 1.f / (1.f + __expf(-(xz + rz)));
            float rg  = 1.f / (1.f + __expf(-(xr + rrg)));
            float pre = xh + rg * rh;
            float hh  = 2.f / (1.f + __expf(-2.f * pre)) - 1.f;  // tanh
            float hold = hT[buf][rl * HP + j];         // fp32 h from LDS
            float o = z * hold + (1.f - z) * hh;
            out[(size_t)row * DD + j] = o;
        }

        if (t + 1 < TPB_GEMM) write_h(buf ^ 1);        // land h t+1 late (T14)
        buf ^= 1;
    }
}

// ---------------------------------------------------------------------------
extern "C" void kernel_launch(void* const* d_in, const int* in_sizes, int n_in,
                              void* d_out, int out_size, void* d_ws, size_t ws_size,
                              hipStream_t stream) {
    const float* atom_state = (const float*)d_in[0];
    const float* messages   = (const float*)d_in[1];
    const int*   conn       = (const int*)d_in[2];
    const float* w0         = (const float*)d_in[3];
    const float* w1         = (const float*)d_in[4];
    const float* bias       = (const float*)d_in[5];
    float* out = (float*)d_out;

    __bf16* wt     = (__bf16*)((char*)d_ws + WT_OFF);
    int*    counts = (int*)((char*)d_ws + CNT_OFF);
    int*    bucket = (int*)((char*)d_ws + BKT_OFF);

    transpose_weights<<<(2 * THREE_D * DD) / 256, 256, 0, stream>>>(w0, w1, wt, counts);
    scatter_ids<<<(BB * EE) / 256, 256, 0, stream>>>(conn, counts, bucket);
    gru_gemm_fused<<<MM / (16 * TPB_GEMM), 512, 0, stream>>>(
        messages, counts, bucket, atom_state, wt, bias, out);
}

// Round 9
// 318.737 us; speedup vs baseline: 1.2267x; 1.0854x over previous
//
#include <hip/hip_runtime.h>
#include <hip/hip_bf16.h>
#include <stdint.h>

// Problem constants (B, N, E, D) = (32, 4096, 8192, 128); all float io fp32.
// R8/R9 (362.4us): LDS-pipelined gemm 106us. R10 (345.9us verified): gather
// fused into gemm staging -> fused 155us (MfmaUtil 6.4%, VALUBusy 24.6%,
// hbm 1.15TB/s, occ 21%). Post-mortem: gather was only ~65us; ~191us sits in
// scatter_ids (262K random global atomics + random 4B stores into 16.8MB,
// ~33MB RMW) + transpose + gaps. Fused kernel +49us vs R9: issue chain was
// cnt->ids->msgs (3 dependent levels, ~1400cyc) into a ~500cyc cover.
// R11: (a) per-batch LDS CSR builder (32 blocks: LDS histogram + prefix scan
// + scatter into compact 1MB CSR; no global atomics, stores confined to
// 32KB L2-window; exact degrees, no CAP truncation), transpose folded in ->
// 2 dispatches total. (b) fused kernel: prologue stages offcnt + 8 ids/node
// into LDS once; per-tile issue = LDS ids -> msg loads (1-level chain, full
// tile of cover). MFMA/h/epilogue byte-identical to verified R10.
// R12: GPU timeout on R11 (never ran). Full audit found no defects
// (scan race-free, cursor/base consistent, pad covered, buffers phase-
// disjoint). Resubmitted unchanged.
#define BB 32
#define NN 4096
#define EE 8192
#define DD 128
#define MM (BB * NN)        // 131072 rows
#define THREE_D (3 * DD)    // 384

typedef __bf16 bf16x8 __attribute__((ext_vector_type(8)));
typedef float  f32x4  __attribute__((ext_vector_type(4)));

// ws layout
#define WT_OFF   0                       // 192 KiB bf16 [mat][col][k]
#define OFFC_OFF ((size_t)1 << 20)       // int2 per node (off, cnt), 1 MiB
#define CSR_OFF  ((size_t)2 << 20)       // BB*EE edge ids + 8 pad, ~1 MiB

// ---------------------------------------------------------------------------
// Kernel 1: blocks 0..31: per-batch CSR build (LDS histogram + prefix +
// scatter). Blocks 32..415: weight transpose fp32->bf16 (D,3D)->(3D,D).
// ---------------------------------------------------------------------------
__global__ __launch_bounds__(256)
void build_tables(const float* __restrict__ w0,
                  const float* __restrict__ w1,
                  const int* __restrict__ conn,
                  __bf16* __restrict__ wt,
                  int2* __restrict__ offcnt,
                  int* __restrict__ csr) {
    if (blockIdx.x >= BB) {
        int tid = (blockIdx.x - BB) * 256 + threadIdx.x;   // 0 .. 98303
        int mat = tid / (THREE_D * DD);
        int rem = tid % (THREE_D * DD);
        int col = rem / DD;
        int k   = rem % DD;
        const float* src = mat ? w1 : w0;
        wt[tid] = (__bf16)src[k * THREE_D + col];
        return;
    }
    __shared__ int tgtL[EE];               // 32 KiB: this batch's targets
    __shared__ int hist[NN];               // 16 KiB: histogram, then cursors
    __shared__ int part[256];
    const int b   = blockIdx.x;
    const int tid = threadIdx.x;
    const int2* c2 = (const int2*)conn + (size_t)b * EE;

    for (int k = 0; k < EE / 256; ++k) {   // A: load targets (coalesced)
        int e = k * 256 + tid;
        tgtL[e] = c2[e].y;
    }
    for (int n = tid; n < NN; n += 256) hist[n] = 0;
    __syncthreads();
    for (int k = 0; k < EE / 256; ++k)     // B: LDS histogram
        atomicAdd(&hist[tgtL[k * 256 + tid]], 1);
    __syncthreads();

    // C: exclusive prefix. Thread t owns 16 counters; scan 256 partials.
    const int c0 = tid * 16;
    int s = 0;
    for (int i = 0; i < 16; ++i) s += hist[c0 + i];
    part[tid] = s;
    __syncthreads();
    for (int d = 1; d < 256; d <<= 1) {    // Hillis-Steele inclusive
        int v = (tid >= d) ? part[tid - d] : 0;
        __syncthreads();
        part[tid] += v;
        __syncthreads();
    }
    int run = part[tid] - s;               // exclusive base of my chunk
    for (int i = 0; i < 16; ++i) {
        int c = hist[c0 + i];
        offcnt[(size_t)b * NN + c0 + i] = (int2){b * EE + run, c};
        hist[c0 + i] = run;                // cursor (batch-local offset)
        run += c;
    }
    __syncthreads();

    for (int k = 0; k < EE / 256; ++k) {   // D: scatter ids (32KB window)
        int e = k * 256 + tid;
        int t = tgtL[e];
        int pos = atomicAdd(&hist[t], 1);
        csr[(size_t)b * EE + pos] = b * EE + e;
    }
}

// ---------------------------------------------------------------------------
// Kernel 2: fused gather + dual-GEMM + GRU gates.
// 512 thr = 8 waves; wave w owns gate-col group g=w. Prologue stages the
// block's 128 nodes' (base, cnt, first 8 ids) into LDS once. Per 16-row
// tile, double-buffered LDS staging: threads 0-255 issue <=4 predicated
// msg loads for t+1 right after the barrier (ids from LDS: 1-level chain);
// MFMA of t covers the latency; accumulate+cvt+ds_write post-MFMA. h fp32
// chunk load-early/ds_write-late (T14). MFMA layouts (gfx950, verified):
// A[m=lane&15][k=quad*8+j], B[k=quad*8+j][n=lane&15], C/D: col=lane&15,
// row=quad*4+reg.
// ---------------------------------------------------------------------------
#define TPB_GEMM 8   // 16-row tiles per block; 128 rows/block -> 1024 blocks
#define AGP 136      // padded agg LDS row (bf16 elems; 272B)
#define HP  132      // padded h   LDS row (f32 elems; 528B)
__launch_bounds__(512, 2)
__global__ void gru_gemm_fused(const float* __restrict__ messages,
                               const int2* __restrict__ offcnt,
                               const int* __restrict__ csr,
                               const float* __restrict__ h_in,
                               const __bf16* __restrict__ wt,
                               const float* __restrict__ bias,
                               float* __restrict__ out) {
    const int tid  = threadIdx.x;
    const int wave = tid >> 6;                         // = gate col group g
    const int lane = tid & 63;
    const int quad = lane >> 4;
    const int l16  = lane & 15;

    __shared__ __bf16 aT[2][16 * AGP];                 // 2 x 4.25 KiB
    __shared__ float  hT[2][16 * HP];                  // 2 x 8.25 KiB
    __shared__ int    idsL[128][8];                    // 4 KiB
    __shared__ int    cntL[128];
    __shared__ int    baseL[128];

    // B fragments [p][m][ko]: wt[(m*384+p*128+g*16+l16)*128 + ko*32+quad*8]
    bf16x8 bfrag[3][2][4];
    for (int p = 0; p < 3; ++p)
        for (int m = 0; m < 2; ++m)
            for (int ko = 0; ko < 4; ++ko)
                bfrag[p][m][ko] = *(const bf16x8*)(wt
                    + ((size_t)(m * THREE_D + p * 128 + wave * 16 + l16)) * DD
                    + ko * 32 + quad * 8);

    const int j = wave * 16 + l16;                     // gate index 0..127
    const float b0z = bias[j];
    const float b0r = bias[DD + j];
    const float b0h = bias[2 * DD + j];
    const float b1z = bias[THREE_D + j];
    const float b1r = bias[THREE_D + DD + j];
    const float b1h = bias[THREE_D + 2 * DD + j];

    const int tile0 = blockIdx.x * TPB_GEMM;

    // prologue: stage this block's 128 nodes' (base, cnt, ids[0..7]) in LDS
    if (tid < 128) {
        int2 oc = offcnt[(size_t)blockIdx.x * 128 + tid];
        baseL[tid] = oc.x;
        cntL[tid]  = oc.y;
        #pragma unroll
        for (int i = 0; i < 8; ++i)                    // speculative (padded)
            idsL[tid][i] = csr[(size_t)oc.x + i];
    }

    // ---- h staging (all 512 threads, 16B each) ----
    f32x4 sh;
    auto load_h = [&](int tb) {
        sh = *(const f32x4*)(h_in + (size_t)tb * 2048 + tid * 4);
    };
    auto write_h = [&](int bf) {
        *(f32x4*)&hT[bf][(tid >> 5) * HP + (tid & 31) * 4] = sh;
    };

    // ---- aggregate staging (threads 0-255; thread owns (row ar, chunk ac))
    const int ar = tid >> 4;                           // row in tile, 0..15
    const int ac = (tid & 15) * 8;                     // first of 8 elems
    int cnt = 0;
    int ids2[4];                                       // ids[4..7] for batch 2
    f32x4 ma[4], mb[4];                                // batch-1 in flight
    auto msg_issue = [&](int rb) {                     // rb = row in block
        if (tid < 256) {
            cnt = cntL[rb];
            int i0 = idsL[rb][0], i1 = idsL[rb][1];
            int i2 = idsL[rb][2], i3 = idsL[rb][3];
            ids2[0] = idsL[rb][4]; ids2[1] = idsL[rb][5];
            ids2[2] = idsL[rb][6]; ids2[3] = idsL[rb][7];
            int e0 = (0 < cnt) ? i0 : 0;
            int e1 = (1 < cnt) ? i1 : 0;
            int e2 = (2 < cnt) ? i2 : 0;
            int e3 = (3 < cnt) ? i3 : 0;
            ma[0] = *(const f32x4*)(messages + (size_t)e0 * DD + ac);
            mb[0] = *(const f32x4*)(messages + (size_t)e0 * DD + ac + 4);
            ma[1] = *(const f32x4*)(messages + (size_t)e1 * DD + ac);
            mb[1] = *(const f32x4*)(messages + (size_t)e1 * DD + ac + 4);
            ma[2] = *(const f32x4*)(messages + (size_t)e2 * DD + ac);
            mb[2] = *(const f32x4*)(messages + (size_t)e2 * DD + ac + 4);
            ma[3] = *(const f32x4*)(messages + (size_t)e3 * DD + ac);
            mb[3] = *(const f32x4*)(messages + (size_t)e3 * DD + ac + 4);
        }
    };
    auto agg_finish = [&](int rb, int bf) {
        if (tid < 256) {
            f32x4 s0 = (f32x4){0.f, 0.f, 0.f, 0.f};
            f32x4 s1 = (f32x4){0.f, 0.f, 0.f, 0.f};
            #pragma unroll
            for (int i = 0; i < 4; ++i)
                if (i < cnt) { s0 += ma[i]; s1 += mb[i]; }
            if (cnt > 4) {                             // ~5% of rows
                #pragma unroll
                for (int i = 4; i < 8; ++i) {
                    int e = (i < cnt) ? ids2[i - 4] : 0;
                    f32x4 va = *(const f32x4*)(messages + (size_t)e * DD + ac);
                    f32x4 vb = *(const f32x4*)(messages + (size_t)e * DD + ac + 4);
                    if (i < cnt) { s0 += va; s1 += vb; }
                }
                for (int i = 8; i < cnt; ++i) {        // ultra-rare tail
                    int e = csr[(size_t)baseL[rb] + i];
                    s0 += *(const f32x4*)(messages + (size_t)e * DD + ac);
                    s1 += *(const f32x4*)(messages + (size_t)e * DD + ac + 4);
                }
            }
            bf16x8 o;
            #pragma unroll
            for (int q = 0; q < 4; ++q) {
                o[q]     = (__bf16)s0[q];
                o[q + 4] = (__bf16)s1[q];
            }
            *(bf16x8*)&aT[bf][ar * AGP + ac] = o;
        }
    };

    __syncthreads();                                   // idsL/cntL ready
    // prologue: stage tile0 into buf 0 (cold, full latency once)
    msg_issue(ar);
    load_h(tile0);
    agg_finish(ar, 0);
    write_h(0);

    int buf = 0;
    for (int t = 0; t < TPB_GEMM; ++t) {
        __syncthreads();                               // buf's tile staged
        const int tb = tile0 + t;
        if (t + 1 < TPB_GEMM) {                        // issue early (T14)
            msg_issue((t + 1) * 16 + ar);
            load_h(tb + 1);
        }

        f32x4 acc[3][2];                               // [part z/r/h][mat]
        for (int p = 0; p < 3; ++p)
            for (int m = 0; m < 2; ++m)
                acc[p][m] = (f32x4){0.f, 0.f, 0.f, 0.f};

        for (int ko = 0; ko < 4; ++ko) {
            bf16x8 af = *(const bf16x8*)&aT[buf][l16 * AGP + ko * 32 + quad * 8];
            f32x4 h0 = *(const f32x4*)&hT[buf][l16 * HP + ko * 32 + quad * 8];
            f32x4 h1 = *(const f32x4*)&hT[buf][l16 * HP + ko * 32 + quad * 8 + 4];
            bf16x8 hg;
            for (int i = 0; i < 4; ++i) {
                hg[i]     = (__bf16)h0[i];
                hg[i + 4] = (__bf16)h1[i];
            }
            for (int p = 0; p < 3; ++p) {
                acc[p][0] = __builtin_amdgcn_mfma_f32_16x16x32_bf16(
                    af, bfrag[p][0][ko], acc[p][0], 0, 0, 0);
                acc[p][1] = __builtin_amdgcn_mfma_f32_16x16x32_bf16(
                    hg, bfrag[p][1][ko], acc[p][1], 0, 0, 0);
            }
        }

        if (t + 1 < TPB_GEMM) agg_finish((t + 1) * 16 + ar, buf ^ 1);

        for (int rr = 0; rr < 4; ++rr) {
            int rl  = quad * 4 + rr;                   // row within tile
            int row = tb * 16 + rl;
            float xz  = acc[0][0][rr] + b0z;
            float rz  = acc[0][1][rr] + b1z;
            float xr  = acc[1][0][rr] + b0r;
            float rrg = acc[1][1][rr] + b1r;
            float xh  = acc[2][0][rr] + b0h;
            float rh  = acc[2][1][rr] + b1h;
            float z   = 1.f / (1.f + __expf(-(xz + rz)));
            float rg  = 1.f / (1.f + __expf(-(xr + rrg)));
            float pre = xh + rg * rh;
            float hh  = 2.f / (1.f + __expf(-2.f * pre)) - 1.f;  // tanh
            float hold = hT[buf][rl * HP + j];         // fp32 h from LDS
            float o = z * hold + (1.f - z) * hh;
            out[(size_t)row * DD + j] = o;
        }

        if (t + 1 < TPB_GEMM) write_h(buf ^ 1);        // land h t+1 late (T14)
        buf ^= 1;
    }
}

// ---------------------------------------------------------------------------
extern "C" void kernel_launch(void* const* d_in, const int* in_sizes, int n_in,
                              void* d_out, int out_size, void* d_ws, size_t ws_size,
                              hipStream_t stream) {
    const float* atom_state = (const float*)d_in[0];
    const float* messages   = (const float*)d_in[1];
    const int*   conn       = (const int*)d_in[2];
    const float* w0         = (const float*)d_in[3];
    const float* w1         = (const float*)d_in[4];
    const float* bias       = (const float*)d_in[5];
    float* out = (float*)d_out;

    __bf16* wt     = (__bf16*)((char*)d_ws + WT_OFF);
    int2*   offcnt = (int2*)((char*)d_ws + OFFC_OFF);
    int*    csr    = (int*)((char*)d_ws + CSR_OFF);

    build_tables<<<BB + (2 * THREE_D * DD) / 256, 256, 0, stream>>>(
        w0, w1, conn, wt, offcnt, csr);
    gru_gemm_fused<<<MM / (16 * TPB_GEMM), 512, 0, stream>>>(
        messages, offcnt, csr, atom_state, wt, bias, out);
}